// Round 4
// baseline (89.815 us; speedup 1.0000x reference)
//
#include <hip/hip_runtime.h>
#include <stdint.h>

typedef unsigned long long u64;
typedef unsigned int u32;

#define NC 80
#define CONF_T 0.25f
#define IOU_THR 0.45f
#define MAX_DET 300
#define KCAND 1024
#define A_ANCH 8400
#define NROWS 84
#define MAX_WH 7680.0f

// ---------------- Kernel 1: per-anchor class max/argmax -> packed sort key ----------------
// key = (score_bits << 32) | ((16383 - anchor) << 7) | cls
// Descending u64 == descending score, ties by ascending anchor (top_k tie-break).
__global__ __launch_bounds__(512) void yolo_conf_kernel(const float* __restrict__ preds,
                                                        u64* __restrict__ keys) {
    int b = blockIdx.x / 9;
    int g = (blockIdx.x % 9) * 512 + threadIdx.x;    // float2 group
    if (g >= A_ANCH / 2) return;
    int a0 = g * 2;
    const float* base = preds + ((size_t)b * NROWS + 4) * A_ANCH + a0;
    float2 best = *(const float2*)base;
    int bc0 = 0, bc1 = 0;
#pragma unroll 8
    for (int c = 1; c < NC; ++c) {
        float2 v = *(const float2*)(base + (size_t)c * A_ANCH);
        if (v.x > best.x) { best.x = v.x; bc0 = c; }   // strict > = first-max argmax
        if (v.y > best.y) { best.y = v.y; bc1 = c; }
    }
    float s0 = (best.x > CONF_T) ? best.x : 0.0f;
    float s1 = (best.y > CONF_T) ? best.y : 0.0f;
    ulonglong2 kk;
    kk.x = ((u64)__float_as_uint(s0) << 32) | ((u64)(16383 - a0) << 7) | (u64)bc0;
    kk.y = ((u64)__float_as_uint(s1) << 32) | ((u64)(16383 - (a0 + 1)) << 7) | (u64)bc1;
    *(ulonglong2*)(keys + (size_t)b * A_ANCH + a0) = kk;
}

__device__ __forceinline__ float iou_f(float ix1, float iy1, float ix2, float iy2, float iar,
                                       float jx1, float jy1, float jx2, float jy2, float jar) {
    float lx = fmaxf(ix1, jx1), ly = fmaxf(iy1, jy1);
    float rx = fminf(ix2, jx2), ry = fminf(iy2, jy2);
    float ww = fmaxf(__fsub_rn(rx, lx), 0.0f);
    float hh = fmaxf(__fsub_rn(ry, ly), 0.0f);
    float inter = __fmul_rn(ww, hh);
    float den = __fadd_rn(__fsub_rn(__fadd_rn(iar, jar), inter), 1e-7f);
    return __fdiv_rn(inter, den);
}

// bitonic compare-exchange step on element idx, partner idx^stride (in-wave, stride<=32)
__device__ __forceinline__ u64 bstep(u64 v, u32 idx, u32 size, u32 stride) {
    u64 v2 = __shfl_xor((unsigned long long)v, (int)stride, 64);
    bool keep_big = (((idx & stride) == 0) == ((idx & size) == 0));
    return ((v > v2) == keep_big) ? v : v2;
}

// ---------------- Kernel 2: exact top-1024 radix select + wave-aggregated compaction ----------------
__global__ __launch_bounds__(1024) void yolo_select_kernel(const u64* __restrict__ keys,
                                                           u64* __restrict__ selk) {
    const int b = blockIdx.x;
    const int tid = threadIdx.x;
    const int lane = tid & 63;
    const int wid = tid >> 6;

    __shared__ u32 sc[A_ANCH];       // 33600 B score bits
    __shared__ u32 hist[4096];       // 16384 B
    __shared__ u32 eqw[264], wpre[264];
    __shared__ u32 s_scal[4];        // 0: P-known-bits, 1: k-remaining, 2: compact count

    const u64* kb = keys + (size_t)b * A_ANCH;
    u32 vals[9];
#pragma unroll
    for (int it = 0; it < 9; ++it) {
        int a = tid + it * 1024;
        vals[it] = (a < A_ANCH) ? (u32)(kb[a] >> 32) : 0u;
    }
    for (int i = tid; i < 4096; i += 1024) hist[i] = 0;
    if (tid == 0) { s_scal[0] = 0; s_scal[1] = KCAND; s_scal[2] = 0; }
#pragma unroll
    for (int it = 0; it < 9; ++it) {
        int a = tid + it * 1024;
        if (a < A_ANCH) sc[a] = vals[it];
    }
    __syncthreads();

    // pass-0 histogram (bits [31:20]) straight from registers; non-returning ds_add
#pragma unroll
    for (int it = 0; it < 9; ++it) {
        int a = tid + it * 1024;
        if (a < A_ANCH) atomicAdd(&hist[vals[it] >> 20], 1u);
    }
    __syncthreads();

    // 3 passes: digits [31:20] (4096), [19:8] (4096), [7:0] (256)
    for (int p = 0; p < 3; ++p) {
        const int shift = (p == 0) ? 20 : (p == 1) ? 8 : 0;
        const int nb = (p == 2) ? 256 : 4096;
        if (wid == 0) {
            // descending-bin suffix scan: lane covers nb/64 contiguous descending digits
            const int per = nb >> 6;
            const int hi0 = nb - 1 - lane * per;
            u32 loc = 0;
            for (int q = 0; q < per; ++q) loc += hist[hi0 - q];
            u32 pre = loc;
            for (int off = 1; off < 64; off <<= 1) {
                u32 o = __shfl_up(pre, off);
                if (lane >= off) pre += o;
            }
            u32 run = pre - loc;
            u32 rem = s_scal[1], Pk = s_scal[0];
            for (int q = 0; q < per; ++q) {
                int d = hi0 - q;
                u32 g = hist[d];
                if (run < rem && rem <= run + g) {
                    s_scal[0] = Pk | ((u32)d << shift);
                    s_scal[1] = rem - run;
                }
                run += g;
            }
        }
        __syncthreads();
        if (p == 2) break;
        // build next pass's histogram among elements matching the known prefix
        const int nshift = (p == 0) ? 8 : 0;
        const u32 nmask = (p == 0) ? 0xFFF00000u : 0xFFFFFF00u;
        const u32 nbm = (p == 0) ? 4095u : 255u;
        for (int i = tid; i < 4096; i += 1024) hist[i] = 0;
        __syncthreads();
        u32 Pk = s_scal[0];
#pragma unroll
        for (int it = 0; it < 9; ++it) {
            int a = tid + it * 1024;
            if (a < A_ANCH) {
                u32 v = sc[a];
                if ((v & nmask) == Pk) atomicAdd(&hist[(v >> nshift) & nbm], 1u);
            }
        }
        __syncthreads();
    }
    const u32 P = s_scal[0];
    const u32 tEq = s_scal[1];   // take tEq lowest-index elements among score==P

    // ---- tie handling: bitmask of score==P + wave-parallel word prefix ----
    if (tid < 264) eqw[tid] = 0;
    __syncthreads();
#pragma unroll
    for (int it = 0; it < 9; ++it) {
        int a = tid + it * 1024;
        if (a < A_ANCH && sc[a] == P) atomicOr(&eqw[a >> 5], 1u << (a & 31));
    }
    __syncthreads();
    if (wid == 0) {
        u32 cnt[5], loc = 0;
#pragma unroll
        for (int q = 0; q < 5; ++q) {
            int w2 = lane * 5 + q;
            u32 e = (w2 < 264) ? eqw[w2] : 0u;
            cnt[q] = (u32)__popc(e); loc += cnt[q];
        }
        u32 pre = loc;
#pragma unroll
        for (int off = 1; off < 64; off <<= 1) {
            u32 o = __shfl_up(pre, off);
            if (lane >= off) pre += o;
        }
        u32 run = pre - loc;
#pragma unroll
        for (int q = 0; q < 5; ++q) {
            int w2 = lane * 5 + q;
            if (w2 < 264) wpre[w2] = run;
            run += cnt[q];
        }
    }
    __syncthreads();

    // ---- wave-aggregated compaction: exactly 1024 keys -> selk (unsorted) ----
    u64* sout = selk + (size_t)b * KCAND;
#pragma unroll
    for (int it = 0; it < 9; ++it) {
        int a = tid + it * 1024;
        bool take = false;
        if (a < A_ANCH) {
            u32 v = sc[a];
            take = v > P;
            if (!take && v == P) {
                u32 r = wpre[a >> 5] + (u32)__popc(eqw[a >> 5] & ((1u << (a & 31)) - 1u));
                take = (r < tEq);
            }
        }
        u64 m = __ballot(take);
        if (m) {
            int fl = __ffsll((unsigned long long)m) - 1;
            u32 base = 0;
            if (lane == fl) base = atomicAdd(&s_scal[2], (u32)__popcll(m));
            base = __shfl(base, fl);
            if (take) sout[base + (u32)__popcll(m & ((1ull << lane) - 1ull))] = kb[a];
        }
    }
}

// ---------------- Kernel 3: hybrid bitonic sort of 1024 keys, descending ----------------
__global__ __launch_bounds__(512) void yolo_sort_kernel(const u64* __restrict__ selk,
                                                        u64* __restrict__ sortk) {
    const int b = blockIdx.x;
    const int tid = threadIdx.x;
    __shared__ u64 skey[KCAND];
    const u64* si = selk + (size_t)b * KCAND;
    u64 vA = si[tid], vB = si[tid + 512];
    const u32 iA = (u32)tid, iB = (u32)tid + 512;
#pragma unroll
    for (u32 size = 2; size <= 64; size <<= 1) {
#pragma unroll
        for (u32 stride = size >> 1; stride >= 1; stride >>= 1) {
            vA = bstep(vA, iA, size, stride);
            vB = bstep(vB, iB, size, stride);
        }
    }
    skey[tid] = vA; skey[tid + 512] = vB;
    __syncthreads();
    for (u32 size = 128; size <= 1024; size <<= 1) {
        for (u32 stride = size >> 1; stride >= 64; stride >>= 1) {
            u32 i1 = ((tid & ~(int)(stride - 1)) << 1) | (tid & (stride - 1));
            u32 i2 = i1 + stride;
            bool desc = ((i1 & size) == 0);
            u64 x = skey[i1], y = skey[i2];
            if ((x < y) == desc) { skey[i1] = y; skey[i2] = x; }
            __syncthreads();
        }
        vA = skey[tid]; vB = skey[tid + 512];
#pragma unroll
        for (u32 stride = 32; stride >= 1; stride >>= 1) {
            vA = bstep(vA, iA, size, stride);
            vB = bstep(vB, iB, size, stride);
        }
        if (size < 1024) { skey[tid] = vA; skey[tid + 512] = vB; __syncthreads(); }
    }
    u64* so = sortk + (size_t)b * KCAND;
    so[tid] = vA; so[tid + 512] = vB;
}

// ---------------- Kernel 4: greedy NMS over sorted candidates + emit ----------------
__global__ __launch_bounds__(512) void yolo_nms_kernel(const float* __restrict__ preds,
                                                       const u64* __restrict__ sortk,
                                                       float* __restrict__ out) {
    const int b = blockIdx.x;
    const int tid = threadIdx.x;
    const int lane = tid & 63;
    const int wid = tid >> 6;

    __shared__ u64 skey[KCAND];
    __shared__ float BX1[KCAND], BY1[KCAND], BX2[KCAND], BY2[KCAND], BAR[KCAND];
    __shared__ u64 rows[64];
    __shared__ int keptlist[364];
    __shared__ float kx1[364], ky1[364], kx2[364], ky2[364], kar[364];
    __shared__ u32 kcls[364];
    __shared__ u32 s_csupp[2];
    __shared__ u32 s_nkept;

    if (tid == 0) { s_csupp[0] = 0; s_csupp[1] = 0; s_nkept = 0; }
    const u64* so = sortk + (size_t)b * KCAND;
#pragma unroll
    for (int q = 0; q < 2; ++q) {
        int t = tid + q * 512;
        u64 key = so[t];
        skey[t] = key;
        int cls = (int)(key & 127u);
        int idx = 16383 - (int)((key >> 7) & 16383u);
        const float* pb = preds + (size_t)b * NROWS * A_ANCH + idx;
        float x = pb[0];
        float y = pb[A_ANCH];
        float w = pb[2 * A_ANCH];
        float h = pb[3 * A_ANCH];
        float hw = __fmul_rn(w, 0.5f), hh = __fmul_rn(h, 0.5f);
        float x1 = __fsub_rn(x, hw), x2 = __fadd_rn(x, hw);
        float y1 = __fsub_rn(y, hh), y2 = __fadd_rn(y, hh);
        float off = __fmul_rn((float)cls, MAX_WH);
        float bx1 = __fadd_rn(x1, off), bx2 = __fadd_rn(x2, off);
        float by1 = __fadd_rn(y1, off), by2 = __fadd_rn(y2, off);
        BX1[t] = bx1; BY1[t] = by1; BX2[t] = bx2; BY2[t] = by2;
        BAR[t] = __fmul_rn(__fsub_rn(bx2, bx1), __fsub_rn(by2, by1));  // area of OFFSET box, as reference
    }
    __syncthreads();

    for (int c = 0; c < KCAND / 64; ++c) {
        int j = c * 64 + lane;
        u64 keyj = skey[j];
        float scj = __uint_as_float((u32)(keyj >> 32));
        u32 clsj = (u32)(keyj & 127u);
        float jx1 = BX1[j], jy1 = BY1[j], jx2 = BX2[j], jy2 = BY2[j], jar = BAR[j];

        // Phase A: chunk candidates vs compact kept list (8 waves strided)
        u32 nk = s_nkept;
        bool suppbit = false;
        for (u32 k = wid; k < nk; k += 8) {
            bool cm = (kcls[k] == clsj);
            if (__ballot(cm)) {    // cross-class IoU exactly 0 (7680 offset) -> skip wave
                float iou = iou_f(kx1[k], ky1[k], kx2[k], ky2[k], kar[k],
                                  jx1, jy1, jx2, jy2, jar);
                suppbit |= (cm && (iou > IOU_THR));
            }
        }
        u64 bm = __ballot(suppbit);
        if (bm && lane == 0) {
            atomicOr(&s_csupp[0], (u32)bm);
            atomicOr(&s_csupp[1], (u32)(bm >> 32));
        }

        // Phase B: in-chunk 64x64 suppression matrix, 8 rows per wave
#pragma unroll
        for (int p2 = 0; p2 < 8; ++p2) {
            int i = p2 * 8 + wid;
            int ci = c * 64 + i;
            u32 clsi = (u32)(skey[ci] & 127u);
            u64 m = 0;
            if (__ballot(clsi == clsj)) {
                float iou = iou_f(BX1[ci], BY1[ci], BX2[ci], BY2[ci], BAR[ci],
                                  jx1, jy1, jx2, jy2, jar);
                m = __ballot((lane > i) && (iou > IOU_THR));
            }
            if (lane == 0) rows[i] = m;
        }
        __syncthreads();

        // Phase C: wave-0 scalar greedy recurrence (readlane -> SGPR chain)
        if (wid == 0) {
            u64 row = rows[lane];
            u32 rlo = (u32)row, rhi = (u32)(row >> 32);
            u64 csupp = (((u64)s_csupp[1]) << 32) | (u64)s_csupp[0];
            u64 valid = __ballot(scj > CONF_T) & ~csupp;
            u64 supp = 0, keep = 0;
#pragma unroll
            for (int i = 0; i < 64; ++i) {
                u64 ri = (((u64)(u32)__builtin_amdgcn_readlane((int)rhi, i)) << 32) |
                         (u64)(u32)__builtin_amdgcn_readlane((int)rlo, i);
                bool ki = (((valid & ~supp) >> i) & 1ull) != 0;
                if (ki) { keep |= (1ull << i); supp |= ri; }
            }
            u32 base = s_nkept;
            if ((keep >> lane) & 1ull) {
                u32 slot = base + (u32)__popcll(keep & ((1ull << lane) - 1ull));
                keptlist[slot] = j;
                kx1[slot] = jx1; ky1[slot] = jy1;
                kx2[slot] = jx2; ky2[slot] = jy2;
                kar[slot] = jar; kcls[slot] = clsj;
            }
            if (lane == 0) {
                s_nkept = base + (u32)__popcll(keep);
                s_csupp[0] = 0; s_csupp[1] = 0;
            }
        }
        __syncthreads();
        if (s_nkept >= MAX_DET) break;   // suppression flows only forward; first 300 fixed
    }

    // ---- emit output rows ----
    if (tid < MAX_DET) {
        u32 nk = s_nkept;
        float row[6];
        int t = (tid < (int)(nk < MAX_DET ? nk : MAX_DET)) ? keptlist[tid] : -1;
        if (t >= 0) {
            u64 key = skey[t];
            float score = __uint_as_float((u32)(key >> 32));
            int cls = (int)(key & 127u);
            int idx = 16383 - (int)((key >> 7) & 16383u);
            const float* pb = preds + (size_t)b * NROWS * A_ANCH + idx;
            float x = pb[0], y = pb[A_ANCH], w = pb[2 * A_ANCH], h = pb[3 * A_ANCH];
            float hw = __fmul_rn(w, 0.5f), hh = __fmul_rn(h, 0.5f);
            row[0] = __fsub_rn(x, hw);
            row[1] = __fsub_rn(y, hh);
            row[2] = __fadd_rn(x, hw);
            row[3] = __fadd_rn(y, hh);
            row[4] = score;
            row[5] = (float)cls;
        } else {
            row[0] = row[1] = row[2] = row[3] = row[4] = row[5] = (float)NC;
        }
        float* o = out + ((size_t)b * MAX_DET + tid) * 6;
#pragma unroll
        for (int q = 0; q < 6; ++q) o[q] = row[q];
    }
}

extern "C" void kernel_launch(void* const* d_in, const int* in_sizes, int n_in,
                              void* d_out, int out_size, void* d_ws, size_t ws_size,
                              hipStream_t stream) {
    const float* preds = (const float*)d_in[0];
    float* out = (float*)d_out;
    int B = in_sizes[0] / (NROWS * A_ANCH);
    u64* keys = (u64*)d_ws;                    // B*8400 u64
    u64* selk = keys + (size_t)B * A_ANCH;     // B*1024 u64
    u64* sortk = selk + (size_t)B * KCAND;     // B*1024 u64  (total ~2.7 MB)
    yolo_conf_kernel<<<dim3(B * 9), dim3(512), 0, stream>>>(preds, keys);
    yolo_select_kernel<<<dim3(B), dim3(1024), 0, stream>>>(keys, selk);
    yolo_sort_kernel<<<dim3(B), dim3(512), 0, stream>>>(selk, sortk);
    yolo_nms_kernel<<<dim3(B), dim3(512), 0, stream>>>(preds, sortk, out);
}